// Round 13
// baseline (132.394 us; speedup 1.0000x reference)
//
#include <hip/hip_runtime.h>
#include <hip/hip_bf16.h>

// Problem constants
// B=8, C=64, H=256, W=256, NH=4, O=16 (HO=64), MX=32, MY=17
#define NROWS 131072
#define MY 17
#define MX 32

// ws layout (floats):
//   Z:    [512, +4456448)      [plane][ky][h] float2  (transposed)
//   X2:   [4456960, +557056)   [(b*64+c)*32+kx][ky] float2

// ---------------------------------------------------------------------------
// F1 = K1+K2 fused, one (b,c) plane per block, 512 threads. (R8, verified)
// ---------------------------------------------------------------------------
#define K1_ROWS 30
#define NCHUNK 9     // 8*30 + 16 = 256

__global__ __launch_bounds__(512) void f1_fw(const float* __restrict__ x,
                                             float2* __restrict__ X2) {
    __shared__ __align__(16) float s_lds[4][K1_ROWS][68];  // 32640 B
    __shared__ float2 xs[4352];                            // 34816 B  [h*17+ky]
    int t = threadIdx.x;
    int bc = blockIdx.x;  // 0..511
    const float* xp = x + (long)bc * 65536;

    // compute-phase constants: thread t<510: j = t%17, row r = t/17 (0..29)
    int j = t % 17;
    int r = t / 17;
    int rc = r < K1_ROWS ? r : 0;  // clamp for pointer init only
    int odd = j & 1;
    float ca = odd ? 0.f : ((j & 2) ? -1.f : 1.f);
    float cb = odd ? (((j & 3) == 1) ? -1.f : 1.f) : 0.f;
    float cj, sj;
    sincospif((float)j * (1.0f / 128.0f), &sj, &cj);
    sj = -sj;  // step e^{-2pi i j/256}
    float swv, cwv;
    sincospif((float)j * 0.25f, &swv, &cwv);
    swv = -swv;  // w8 = e^{-pi i j/4}
    float k1c = cwv * ca - swv * cb;
    float k2c = swv * ca + cwv * cb;
    const float4* A4 = (const float4*)&s_lds[odd ? 1 : 0][rc][0];
    const float4* B4 = (const float4*)&s_lds[odd ? 3 : 2][rc][0];

    float4 q0, q1, q2, q3;

#define F1_REGLOAD(cc)                                                         \
    {                                                                          \
        int nr_ = ((cc) < 8) ? K1_ROWS : 16;                                   \
        int items_ = nr_ * 16;                                                 \
        int it = t < items_ ? t : items_ - 1;                                  \
        int rr = it >> 4, cq = it & 15;                                        \
        const float4* xr =                                                     \
            (const float4*)(xp + ((cc) * K1_ROWS + rr) * 256) + cq;            \
        q0 = xr[0];                                                            \
        q1 = xr[16];                                                           \
        q2 = xr[32];                                                           \
        q3 = xr[48];                                                           \
    }

    F1_REGLOAD(0)

    for (int c = 0; c < NCHUNK; ++c) {
        int nr = (c < 8) ? K1_ROWS : 16;
        int items = nr * 16;

        // radix-4 combine (along w) + LDS write, from registers
        if (t < items) {
            int rr = t >> 4, cq = t & 15;
            float4 s02p, s02m, s13p, s13m;
            s02p.x = q0.x + q2.x; s02p.y = q0.y + q2.y;
            s02p.z = q0.z + q2.z; s02p.w = q0.w + q2.w;
            s02m.x = q0.x - q2.x; s02m.y = q0.y - q2.y;
            s02m.z = q0.z - q2.z; s02m.w = q0.w - q2.w;
            s13p.x = q1.x + q3.x; s13p.y = q1.y + q3.y;
            s13p.z = q1.z + q3.z; s13p.w = q1.w + q3.w;
            s13m.x = q1.x - q3.x; s13m.y = q1.y - q3.y;
            s13m.z = q1.z - q3.z; s13m.w = q1.w - q3.w;
            *(float4*)&s_lds[0][rr][cq * 4] = s02p;
            *(float4*)&s_lds[1][rr][cq * 4] = s02m;
            *(float4*)&s_lds[2][rr][cq * 4] = s13p;
            *(float4*)&s_lds[3][rr][cq * 4] = s13m;
        }
        __syncthreads();

        // prefetch next chunk into registers (in flight during compute)
        if (c + 1 < NCHUNK) F1_REGLOAD(c + 1)

        // 17-mode DFT of this chunk (radix-2 over l: 32 steps), 1 row/thread
        if (t < 510 && r < nr) {
            float pc = 1.f, ps = 0.f;
            float ar0 = 0, ai0 = 0;

#define K1_STEP(a0e, b0e, a0f, b0f)                                   \
  { float t0re = fmaf(k1c, (b0f), fmaf(cwv, (a0f), fmaf(ca, (b0e), (a0e)))); \
    float t0im = fmaf(k2c, (b0f), fmaf(swv, (a0f), cb * (b0e)));      \
    ar0 = fmaf(t0re, pc, ar0); ar0 = fmaf(-t0im, ps, ar0);            \
    ai0 = fmaf(t0re, ps, ai0); ai0 = fmaf(t0im, pc, ai0);             \
    float nps = fmaf(pc, sj, ps * cj);                                \
    pc = fmaf(pc, cj, -(ps * sj)); ps = nps; }

#pragma unroll 2
            for (int l4 = 0; l4 < 8; ++l4) {
                float4 va0 = A4[l4], vb0 = B4[l4];
                float4 vA0 = A4[8 + l4], vB0 = B4[8 + l4];  // l+32
                K1_STEP(va0.x, vb0.x, vA0.x, vB0.x)
                K1_STEP(va0.y, vb0.y, vA0.y, vB0.y)
                K1_STEP(va0.z, vb0.z, vA0.z, vB0.z)
                K1_STEP(va0.w, vb0.w, vA0.w, vB0.w)
            }
#undef K1_STEP

            int h = c * K1_ROWS + r;
            xs[h * 17 + j] = make_float2(ar0, ai0);
        }
        __syncthreads();
    }

    // K2: in-place radix-4 butterfly along h (stage 1: h vs h+128)
    for (int q = t; q < 2176; q += 512) {
        float2 a = xs[q], b = xs[q + 2176];
        xs[q] = make_float2(a.x + b.x, a.y + b.y);
        xs[q + 2176] = make_float2(a.x - b.x, a.y - b.y);
    }
    __syncthreads();

    for (int q = t; q < 544; q += 512) {
        int kx = q / 17, ky = q % 17;
        int kodd = kx & 1;
        float cA = kodd ? 0.f : ((kx & 2) ? -1.f : 1.f);
        float cB = kodd ? (((kx & 3) == 1) ? -1.f : 1.f) : 0.f;
        float cBn = -cB;
        const float2* Aq = xs + (kodd ? 2176 : 0) + ky;
        float cs, ss;
        sincospif((float)kx * (1.0f / 128.0f), &ss, &cs);
        ss = -ss;  // step e^{-2pi i kx/256}
        float pc = 1.f, psn = 0.f;
        float ar = 0.f, ai = 0.f;
#pragma unroll 4
        for (int m = 0; m < 64; ++m) {
            float2 a = Aq[m * 17];
            float2 b = Aq[1088 + m * 17];
            float yre = fmaf(cBn, b.y, fmaf(cA, b.x, a.x));
            float yim = fmaf(cB, b.x, fmaf(cA, b.y, a.y));
            ar = fmaf(yre, pc, ar); ar = fmaf(-yim, psn, ar);
            ai = fmaf(yre, psn, ai); ai = fmaf(yim, pc, ai);
            float npc = pc * cs - psn * ss;
            psn = pc * ss + psn * cs;
            pc = npc;
        }
        X2[(long)bc * 544 + q] = make_float2(ar, ai);
    }
#undef F1_REGLOAD
}

// ---------------------------------------------------------------------------
// K_AB = k3+K4, one (b,ho) plane per block, 512 threads. (R11, verified)
// ---------------------------------------------------------------------------
__global__ __launch_bounds__(512) void k_ab(const float2* __restrict__ X2,
                                            const float* __restrict__ wr_g,
                                            const float* __restrict__ wi_g,
                                            float2* __restrict__ Z) {
    __shared__ float2 psh[544];
    int t = threadIdx.x;
    int plane = blockIdx.x;  // 0..511 = b*64 + ho
    int b = plane >> 6;
    int ho = plane & 63;
    int n = ho >> 4;
    int o = ho & 15;

    // Phase A: per-(kx,ky) 64-deep channel reduction (linear i order)
    for (int q = t; q < 544; q += 512) {
        const float2* xp = X2 + (long)b * 64 * 544 + q;
        const float* wrp = wr_g + ((long)(n * 64) * 16 + o) * 544 + q;
        const float* wip = wi_g + ((long)(n * 64) * 16 + o) * 544 + q;
        float ar = 0.f, ai = 0.f;
#pragma unroll 4
        for (int i = 0; i < 64; ++i) {
            float2 xv = xp[i * 544];
            float wvr = wrp[i * 8704];
            float wvi = wip[i * 8704];
            ar += xv.x * wvr - xv.y * wvi;
            ai += xv.x * wvi + xv.y * wvr;
        }
        psh[q] = make_float2(ar, ai);
    }
    __syncthreads();

    // Phase B (K4): h = t&255, half = t>>8 (wave-uniform), write Z transposed
    {
        int h = t & 255;
        int half = t >> 8;
        int kyb = half ? 9 : 0;
        int cnt = half ? 8 : 9;
        float chh, shh;
        sincospif((float)h * (1.0f / 128.0f), &shh, &chh);
        float pc = 1.f, psn = 0.f;
        float ar[9], ai[9];
#pragma unroll
        for (int u = 0; u < 9; ++u) { ar[u] = 0.f; ai[u] = 0.f; }

        const float2* pq = psh + kyb;
        for (int kx = 0; kx < 32; ++kx) {
#pragma unroll
            for (int u = 0; u < 9; ++u) {
                if (u < cnt) {
                    float2 v = pq[kx * 17 + u];
                    ar[u] += v.x * pc - v.y * psn;
                    ai[u] += v.x * psn + v.y * pc;
                }
            }
            float npc = pc * chh - psn * shh;
            psn = pc * shh + psn * chh;
            pc = npc;
        }
        float2* zp = Z + (long)plane * 4352 + h;
#pragma unroll
        for (int u = 0; u < 9; ++u)
            if (u < cnt) zp[(kyb + u) * 256] = make_float2(ar[u], ai[u]);
    }
}

// ---------------------------------------------------------------------------
// K_C = K5, 8 row-groups per plane (grid 4096), 256 threads, NO LDS.
//  Z reads are wave-uniform (plane/base from blockIdx, r0 from readfirstlane,
//  ky compile-time) -> scalar/broadcast loads; LDS pipe untouched.
//  ky-fold: zz[m] = z[m] + z[m+8]*e^{i*8θ}; e^{i8θ} identical for all four
//  w-offsets of a lane (8*64/256 = 2 full turns) -> fold shared, loop ky=1..8.
// ---------------------------------------------------------------------------
__global__ __launch_bounds__(256) void k_c(const float2* __restrict__ Z,
                                           const float* __restrict__ bias,
                                           float* __restrict__ out) {
    int t = threadIdx.x;
    int bi = blockIdx.x;
    int plane = bi >> 3;       // 0..511
    int base = (bi & 7) * 32;  // row group
    int wv = __builtin_amdgcn_readfirstlane(t >> 6);  // 0..3, wave-uniform
    int lane = t & 63;
    float bv = bias[plane & 63];

    float c0, s0;
    sincospif((float)lane * (1.0f / 128.0f), &s0, &c0);  // e^{2pi i lane/256}
    float c8, s8;
    sincospif((float)lane * (1.0f / 16.0f), &s8, &c8);   // e^{2pi i 8 lane/256}

    const float2* zp = Z + (long)plane * 4352 + base;
    const float inv = 1.0f / 65536.0f;
    const float inv2 = 2.0f / 65536.0f;
    long ob_plane = (long)plane * 65536 + (long)base * 256;

    for (int it = 0; it < 4; ++it) {
        int r0 = it * 8 + wv * 2;  // wave-uniform local row
        const float2* zr0 = zp + r0;
        const float2* zr1 = zp + r0 + 1;

        float dc0 = zr0[0].x, dc1 = zr1[0].x;
        float zz0r[9], zz0i[9], zz1r[9], zz1i[9];
#pragma unroll
        for (int ky = 1; ky <= 8; ++ky) {
            float2 a0 = zr0[ky * 256], b0 = zr0[(ky + 8) * 256];
            float2 a1 = zr1[ky * 256], b1 = zr1[(ky + 8) * 256];
            zz0r[ky - 1] = fmaf(b0.x, c8, fmaf(-b0.y, s8, a0.x));
            zz0i[ky - 1] = fmaf(b0.x, s8, fmaf(b0.y, c8, a0.y));
            zz1r[ky - 1] = fmaf(b1.x, c8, fmaf(-b1.y, s8, a1.x));
            zz1i[ky - 1] = fmaf(b1.x, s8, fmaf(b1.y, c8, a1.y));
        }

        float pc = c0, psn = s0;  // phasor at ky=1
        float a00 = 0, a01 = 0, a02 = 0, a03 = 0;
        float a10 = 0, a11 = 0, a12 = 0, a13 = 0;
#pragma unroll
        for (int ky = 1; ky <= 8; ++ky) {
            float zr0v = zz0r[ky - 1], zi0v = zz0i[ky - 1];
            float zr1v = zz1r[ky - 1], zi1v = zz1i[ky - 1];
            float A0 = zr0v * pc - zi0v * psn;
            float B0 = zr0v * psn + zi0v * pc;
            float A1 = zr1v * pc - zi1v * psn;
            float B1 = zr1v * psn + zi1v * pc;
            a00 += A0; a10 += A1;
            a01 += ((ky & 3) == 0) ? A0 : ((ky & 3) == 1) ? -B0 : ((ky & 3) == 2) ? -A0 : B0;
            a11 += ((ky & 3) == 0) ? A1 : ((ky & 3) == 1) ? -B1 : ((ky & 3) == 2) ? -A1 : B1;
            a02 += (ky & 1) ? -A0 : A0;
            a12 += (ky & 1) ? -A1 : A1;
            a03 += ((ky & 3) == 0) ? A0 : ((ky & 3) == 1) ? B0 : ((ky & 3) == 2) ? -A0 : -B0;
            a13 += ((ky & 3) == 0) ? A1 : ((ky & 3) == 1) ? B1 : ((ky & 3) == 2) ? -A1 : -B1;
            float npc = pc * c0 - psn * s0;
            psn = pc * s0 + psn * c0;
            pc = npc;
        }
        float base0 = dc0 * inv + bv;
        float base1 = dc1 * inv + bv;
        long ob0 = ob_plane + (long)r0 * 256;
        long ob1 = ob0 + 256;
        out[ob0 + lane]       = fmaf(a00, inv2, base0);
        out[ob0 + 64 + lane]  = fmaf(a01, inv2, base0);
        out[ob0 + 128 + lane] = fmaf(a02, inv2, base0);
        out[ob0 + 192 + lane] = fmaf(a03, inv2, base0);
        out[ob1 + lane]       = fmaf(a10, inv2, base1);
        out[ob1 + 64 + lane]  = fmaf(a11, inv2, base1);
        out[ob1 + 128 + lane] = fmaf(a12, inv2, base1);
        out[ob1 + 192 + lane] = fmaf(a13, inv2, base1);
    }
}

extern "C" void kernel_launch(void* const* d_in, const int* in_sizes, int n_in,
                              void* d_out, int out_size, void* d_ws, size_t ws_size,
                              hipStream_t stream) {
    const float* x = (const float*)d_in[0];
    const float* wr = (const float*)d_in[1];
    const float* wi = (const float*)d_in[2];
    const float* bias = (const float*)d_in[3];
    float* out = (float*)d_out;
    float* ws = (float*)d_ws;

    float2* Z  = (float2*)(ws + 512);
    float2* X2 = (float2*)(ws + 4456960);

    hipLaunchKernelGGL(f1_fw, dim3(512), dim3(512), 0, stream, x, X2);
    hipLaunchKernelGGL(k_ab, dim3(512), dim3(512), 0, stream, X2, wr, wi, Z);
    hipLaunchKernelGGL(k_c, dim3(4096), dim3(256), 0, stream, Z, bias, out);
}

// Round 14
// 115.104 us; speedup vs baseline: 1.1502x; 1.1502x over previous
//
#include <hip/hip_runtime.h>
#include <hip/hip_bf16.h>

// Problem constants
// B=8, C=64, H=256, W=256, NH=4, O=16 (HO=64), MX=32, MY=17
#define NROWS 131072
#define MY 17
#define MX 32

// ws layout (floats):
//   X2:   [4456960, +557056)   [(b*64+c)*32+kx][ky] float2

// ---------------------------------------------------------------------------
// F1 = K1+K2 fused, one (b,c) plane per block, 512 threads. (R8, verified)
// ---------------------------------------------------------------------------
#define K1_ROWS 30
#define NCHUNK 9     // 8*30 + 16 = 256

__global__ __launch_bounds__(512) void f1_fw(const float* __restrict__ x,
                                             float2* __restrict__ X2) {
    __shared__ __align__(16) float s_lds[4][K1_ROWS][68];  // 32640 B
    __shared__ float2 xs[4352];                            // 34816 B  [h*17+ky]
    int t = threadIdx.x;
    int bc = blockIdx.x;  // 0..511
    const float* xp = x + (long)bc * 65536;

    // compute-phase constants: thread t<510: j = t%17, row r = t/17 (0..29)
    int j = t % 17;
    int r = t / 17;
    int rc = r < K1_ROWS ? r : 0;  // clamp for pointer init only
    int odd = j & 1;
    float ca = odd ? 0.f : ((j & 2) ? -1.f : 1.f);
    float cb = odd ? (((j & 3) == 1) ? -1.f : 1.f) : 0.f;
    float cj, sj;
    sincospif((float)j * (1.0f / 128.0f), &sj, &cj);
    sj = -sj;  // step e^{-2pi i j/256}
    float swv, cwv;
    sincospif((float)j * 0.25f, &swv, &cwv);
    swv = -swv;  // w8 = e^{-pi i j/4}
    float k1c = cwv * ca - swv * cb;
    float k2c = swv * ca + cwv * cb;
    const float4* A4 = (const float4*)&s_lds[odd ? 1 : 0][rc][0];
    const float4* B4 = (const float4*)&s_lds[odd ? 3 : 2][rc][0];

    float4 q0, q1, q2, q3;

#define F1_REGLOAD(cc)                                                         \
    {                                                                          \
        int nr_ = ((cc) < 8) ? K1_ROWS : 16;                                   \
        int items_ = nr_ * 16;                                                 \
        int it = t < items_ ? t : items_ - 1;                                  \
        int rr = it >> 4, cq = it & 15;                                        \
        const float4* xr =                                                     \
            (const float4*)(xp + ((cc) * K1_ROWS + rr) * 256) + cq;            \
        q0 = xr[0];                                                            \
        q1 = xr[16];                                                           \
        q2 = xr[32];                                                           \
        q3 = xr[48];                                                           \
    }

    F1_REGLOAD(0)

    for (int c = 0; c < NCHUNK; ++c) {
        int nr = (c < 8) ? K1_ROWS : 16;
        int items = nr * 16;

        // radix-4 combine (along w) + LDS write, from registers
        if (t < items) {
            int rr = t >> 4, cq = t & 15;
            float4 s02p, s02m, s13p, s13m;
            s02p.x = q0.x + q2.x; s02p.y = q0.y + q2.y;
            s02p.z = q0.z + q2.z; s02p.w = q0.w + q2.w;
            s02m.x = q0.x - q2.x; s02m.y = q0.y - q2.y;
            s02m.z = q0.z - q2.z; s02m.w = q0.w - q2.w;
            s13p.x = q1.x + q3.x; s13p.y = q1.y + q3.y;
            s13p.z = q1.z + q3.z; s13p.w = q1.w + q3.w;
            s13m.x = q1.x - q3.x; s13m.y = q1.y - q3.y;
            s13m.z = q1.z - q3.z; s13m.w = q1.w - q3.w;
            *(float4*)&s_lds[0][rr][cq * 4] = s02p;
            *(float4*)&s_lds[1][rr][cq * 4] = s02m;
            *(float4*)&s_lds[2][rr][cq * 4] = s13p;
            *(float4*)&s_lds[3][rr][cq * 4] = s13m;
        }
        __syncthreads();

        // prefetch next chunk into registers (in flight during compute)
        if (c + 1 < NCHUNK) F1_REGLOAD(c + 1)

        // 17-mode DFT of this chunk (radix-2 over l: 32 steps), 1 row/thread
        if (t < 510 && r < nr) {
            float pc = 1.f, ps = 0.f;
            float ar0 = 0, ai0 = 0;

#define K1_STEP(a0e, b0e, a0f, b0f)                                   \
  { float t0re = fmaf(k1c, (b0f), fmaf(cwv, (a0f), fmaf(ca, (b0e), (a0e)))); \
    float t0im = fmaf(k2c, (b0f), fmaf(swv, (a0f), cb * (b0e)));      \
    ar0 = fmaf(t0re, pc, ar0); ar0 = fmaf(-t0im, ps, ar0);            \
    ai0 = fmaf(t0re, ps, ai0); ai0 = fmaf(t0im, pc, ai0);             \
    float nps = fmaf(pc, sj, ps * cj);                                \
    pc = fmaf(pc, cj, -(ps * sj)); ps = nps; }

#pragma unroll 2
            for (int l4 = 0; l4 < 8; ++l4) {
                float4 va0 = A4[l4], vb0 = B4[l4];
                float4 vA0 = A4[8 + l4], vB0 = B4[8 + l4];  // l+32
                K1_STEP(va0.x, vb0.x, vA0.x, vB0.x)
                K1_STEP(va0.y, vb0.y, vA0.y, vB0.y)
                K1_STEP(va0.z, vb0.z, vA0.z, vB0.z)
                K1_STEP(va0.w, vb0.w, vA0.w, vB0.w)
            }
#undef K1_STEP

            int h = c * K1_ROWS + r;
            xs[h * 17 + j] = make_float2(ar0, ai0);
        }
        __syncthreads();
    }

    // K2: in-place radix-4 butterfly along h (stage 1: h vs h+128)
    for (int q = t; q < 2176; q += 512) {
        float2 a = xs[q], b = xs[q + 2176];
        xs[q] = make_float2(a.x + b.x, a.y + b.y);
        xs[q + 2176] = make_float2(a.x - b.x, a.y - b.y);
    }
    __syncthreads();

    for (int q = t; q < 544; q += 512) {
        int kx = q / 17, ky = q % 17;
        int kodd = kx & 1;
        float cA = kodd ? 0.f : ((kx & 2) ? -1.f : 1.f);
        float cB = kodd ? (((kx & 3) == 1) ? -1.f : 1.f) : 0.f;
        float cBn = -cB;
        const float2* Aq = xs + (kodd ? 2176 : 0) + ky;
        float cs, ss;
        sincospif((float)kx * (1.0f / 128.0f), &ss, &cs);
        ss = -ss;  // step e^{-2pi i kx/256}
        float pc = 1.f, psn = 0.f;
        float ar = 0.f, ai = 0.f;
#pragma unroll 4
        for (int m = 0; m < 64; ++m) {
            float2 a = Aq[m * 17];
            float2 b = Aq[1088 + m * 17];
            float yre = fmaf(cBn, b.y, fmaf(cA, b.x, a.x));
            float yim = fmaf(cB, b.x, fmaf(cA, b.y, a.y));
            ar = fmaf(yre, pc, ar); ar = fmaf(-yim, psn, ar);
            ai = fmaf(yre, psn, ai); ai = fmaf(yim, pc, ai);
            float npc = pc * cs - psn * ss;
            psn = pc * ss + psn * cs;
            pc = npc;
        }
        X2[(long)bc * 544 + q] = make_float2(ar, ai);
    }
#undef F1_REGLOAD
}

// ---------------------------------------------------------------------------
// F2C = k3+K4+K5 fused, one (b,ho) plane per block, 512 threads (R9 shape).
//  Phase A (k3, verified): psh[kx][ky] = sum_i X2[b,i,kx,ky]*(wr+i wi)[...]
//  Phase B (K4, h-pair radix-2): thread owns (h, h+128), h = t&127;
//    even/odd-kx accumulators: Z[h] = E+O, Z[h+128] = E-O
//    ky group by t>>7: grp0 ky0-4, grp1 5-8, grp2 9-12, grp3 13-16
//  Phase C (K5, ky-fold verified R12 + hoisted phasor table):
//    8 waves x 2 rows x 16 iters
// ---------------------------------------------------------------------------
__global__ __launch_bounds__(512) void f2c_inv(const float2* __restrict__ X2,
                                               const float* __restrict__ wr_g,
                                               const float* __restrict__ wi_g,
                                               const float* __restrict__ bias,
                                               float* __restrict__ out) {
    __shared__ float2 psh[544];
    __shared__ float2 zsh[4352];  // [h*17+ky]
    int t = threadIdx.x;
    int plane = blockIdx.x;  // 0..511 = b*64 + ho
    int b = plane >> 6;
    int ho = plane & 63;
    int n = ho >> 4;
    int o = ho & 15;

    // Phase A: per-(kx,ky) 64-deep channel reduction (verified, linear i order)
    for (int q = t; q < 544; q += 512) {
        const float2* xp = X2 + (long)b * 64 * 544 + q;
        const float* wrp = wr_g + ((long)(n * 64) * 16 + o) * 544 + q;
        const float* wip = wi_g + ((long)(n * 64) * 16 + o) * 544 + q;
        float ar = 0.f, ai = 0.f;
#pragma unroll 4
        for (int i = 0; i < 64; ++i) {
            float2 xv = xp[i * 544];
            float wvr = wrp[i * 8704];
            float wvi = wip[i * 8704];
            ar += xv.x * wvr - xv.y * wvi;
            ai += xv.x * wvi + xv.y * wvr;
        }
        psh[q] = make_float2(ar, ai);
    }
    __syncthreads();

    // Phase B: h-pair radix-2 over kx. h = t&127, pair (h, h+128).
    {
        int h = t & 127;
        int grp = t >> 7;                        // 0..3, wave-uniform
        int kyb = (grp == 0) ? 0 : (4 * grp + 1);  // 0,5,9,13
        int cnt = (grp == 0) ? 5 : 4;
        float chh, shh;
        sincospif((float)h * (1.0f / 128.0f), &shh, &chh);  // step e^{+2pi i h/256}
        float pc = 1.f, psn = 0.f;
        float aer[5], aei[5], aor[5], aoi[5];
#pragma unroll
        for (int u = 0; u < 5; ++u) { aer[u] = 0.f; aei[u] = 0.f; aor[u] = 0.f; aoi[u] = 0.f; }

        const float2* pq = psh + kyb;
#pragma unroll
        for (int kx = 0; kx < 32; ++kx) {
#pragma unroll
            for (int u = 0; u < 5; ++u) {
                if (u < cnt) {
                    float2 v = pq[kx * 17 + u];
                    if ((kx & 1) == 0) {
                        aer[u] = fmaf(v.x, pc, fmaf(-v.y, psn, aer[u]));
                        aei[u] = fmaf(v.x, psn, fmaf(v.y, pc, aei[u]));
                    } else {
                        aor[u] = fmaf(v.x, pc, fmaf(-v.y, psn, aor[u]));
                        aoi[u] = fmaf(v.x, psn, fmaf(v.y, pc, aoi[u]));
                    }
                }
            }
            float npc = pc * chh - psn * shh;
            psn = pc * shh + psn * chh;
            pc = npc;
        }
#pragma unroll
        for (int u = 0; u < 5; ++u) {
            if (u < cnt) {
                int ky = kyb + u;
                zsh[h * 17 + ky] = make_float2(aer[u] + aor[u], aei[u] + aoi[u]);
                zsh[(h + 128) * 17 + ky] = make_float2(aer[u] - aor[u], aei[u] - aoi[u]);
            }
        }
    }
    __syncthreads();

    // Phase C: ky-fold (pairs ky,ky+8 share e^{2pi i 8 w/256} across all four
    // w-offsets; i^(ky+8) == i^ky so sign patterns unchanged — verified R12)
    // + phasor table hoisted out of the row loop.
    int wv = t >> 6;      // 0..7
    int lane = t & 63;
    float bv = bias[plane & 63];
    float c0, s0;
    sincospif((float)lane * (1.0f / 128.0f), &s0, &c0);  // e^{2pi i lane/256}
    float c8, s8;
    sincospif((float)lane * (1.0f / 16.0f), &s8, &c8);   // e^{2pi i 8 lane/256}

    float pcv[8], psv[8];
    {
        float pc = c0, ps = s0;
#pragma unroll
        for (int k = 0; k < 8; ++k) {
            pcv[k] = pc; psv[k] = ps;
            float nps = fmaf(pc, s0, ps * c0);
            pc = fmaf(pc, c0, -(ps * s0));
            ps = nps;
        }
    }

    const float inv = 1.0f / 65536.0f;
    const float inv2 = 2.0f / 65536.0f;
    long ob_plane = (long)plane * 65536;

    for (int it16 = 0; it16 < 16; ++it16) {
        int r0 = it16 * 16 + wv * 2;

        float zz0r[8], zz0i[8], zz1r[8], zz1i[8];
#pragma unroll
        for (int k = 0; k < 8; ++k) {
            int ky = k + 1;
            float2 a0 = zsh[r0 * 17 + ky];
            float2 b0 = zsh[r0 * 17 + ky + 8];
            float2 a1 = zsh[(r0 + 1) * 17 + ky];
            float2 b1 = zsh[(r0 + 1) * 17 + ky + 8];
            zz0r[k] = fmaf(b0.x, c8, fmaf(-b0.y, s8, a0.x));
            zz0i[k] = fmaf(b0.x, s8, fmaf(b0.y, c8, a0.y));
            zz1r[k] = fmaf(b1.x, c8, fmaf(-b1.y, s8, a1.x));
            zz1i[k] = fmaf(b1.x, s8, fmaf(b1.y, c8, a1.y));
        }

        float a00 = 0, a01 = 0, a02 = 0, a03 = 0;
        float a10 = 0, a11 = 0, a12 = 0, a13 = 0;
#pragma unroll
        for (int k = 0; k < 8; ++k) {
            int ky = k + 1;
            float A0 = zz0r[k] * pcv[k] - zz0i[k] * psv[k];
            float B0 = zz0r[k] * psv[k] + zz0i[k] * pcv[k];
            float A1 = zz1r[k] * pcv[k] - zz1i[k] * psv[k];
            float B1 = zz1r[k] * psv[k] + zz1i[k] * pcv[k];
            a00 += A0; a10 += A1;
            a01 += ((ky & 3) == 0) ? A0 : ((ky & 3) == 1) ? -B0 : ((ky & 3) == 2) ? -A0 : B0;
            a11 += ((ky & 3) == 0) ? A1 : ((ky & 3) == 1) ? -B1 : ((ky & 3) == 2) ? -A1 : B1;
            a02 += (ky & 1) ? -A0 : A0;
            a12 += (ky & 1) ? -A1 : A1;
            a03 += ((ky & 3) == 0) ? A0 : ((ky & 3) == 1) ? B0 : ((ky & 3) == 2) ? -A0 : -B0;
            a13 += ((ky & 3) == 0) ? A1 : ((ky & 3) == 1) ? B1 : ((ky & 3) == 2) ? -A1 : -B1;
        }
        float base0 = zsh[r0 * 17].x * inv + bv;
        float base1 = zsh[(r0 + 1) * 17].x * inv + bv;
        long ob0 = ob_plane + (long)r0 * 256;
        long ob1 = ob0 + 256;
        out[ob0 + lane]       = fmaf(a00, inv2, base0);
        out[ob0 + 64 + lane]  = fmaf(a01, inv2, base0);
        out[ob0 + 128 + lane] = fmaf(a02, inv2, base0);
        out[ob0 + 192 + lane] = fmaf(a03, inv2, base0);
        out[ob1 + lane]       = fmaf(a10, inv2, base1);
        out[ob1 + 64 + lane]  = fmaf(a11, inv2, base1);
        out[ob1 + 128 + lane] = fmaf(a12, inv2, base1);
        out[ob1 + 192 + lane] = fmaf(a13, inv2, base1);
    }
}

extern "C" void kernel_launch(void* const* d_in, const int* in_sizes, int n_in,
                              void* d_out, int out_size, void* d_ws, size_t ws_size,
                              hipStream_t stream) {
    const float* x = (const float*)d_in[0];
    const float* wr = (const float*)d_in[1];
    const float* wi = (const float*)d_in[2];
    const float* bias = (const float*)d_in[3];
    float* out = (float*)d_out;
    float* ws = (float*)d_ws;

    float2* X2 = (float2*)(ws + 4456960);

    hipLaunchKernelGGL(f1_fw, dim3(512), dim3(512), 0, stream, x, X2);
    hipLaunchKernelGGL(f2c_inv, dim3(512), dim3(512), 0, stream, X2, wr, wi, bias, out);
}

// Round 15
// 109.873 us; speedup vs baseline: 1.2050x; 1.0476x over previous
//
#include <hip/hip_runtime.h>
#include <hip/hip_bf16.h>

// Problem constants
// B=8, C=64, H=256, W=256, NH=4, O=16 (HO=64), MX=32, MY=17
#define NROWS 131072
#define MY 17
#define MX 32

// ws layout (floats):
//   X2:   [4456960, +557056)   [(b*64+c)*32+kx][ky] float2

// ---------------------------------------------------------------------------
// F1 = K1+K2 fused, one (b,c) plane per block, 512 threads. (R8, verified)
// ---------------------------------------------------------------------------
#define K1_ROWS 30
#define NCHUNK 9     // 8*30 + 16 = 256

__global__ __launch_bounds__(512) void f1_fw(const float* __restrict__ x,
                                             float2* __restrict__ X2) {
    __shared__ __align__(16) float s_lds[4][K1_ROWS][68];  // 32640 B
    __shared__ float2 xs[4352];                            // 34816 B  [h*17+ky]
    int t = threadIdx.x;
    int bc = blockIdx.x;  // 0..511
    const float* xp = x + (long)bc * 65536;

    // compute-phase constants: thread t<510: j = t%17, row r = t/17 (0..29)
    int j = t % 17;
    int r = t / 17;
    int rc = r < K1_ROWS ? r : 0;  // clamp for pointer init only
    int odd = j & 1;
    float ca = odd ? 0.f : ((j & 2) ? -1.f : 1.f);
    float cb = odd ? (((j & 3) == 1) ? -1.f : 1.f) : 0.f;
    float cj, sj;
    sincospif((float)j * (1.0f / 128.0f), &sj, &cj);
    sj = -sj;  // step e^{-2pi i j/256}
    float swv, cwv;
    sincospif((float)j * 0.25f, &swv, &cwv);
    swv = -swv;  // w8 = e^{-pi i j/4}
    float k1c = cwv * ca - swv * cb;
    float k2c = swv * ca + cwv * cb;
    const float4* A4 = (const float4*)&s_lds[odd ? 1 : 0][rc][0];
    const float4* B4 = (const float4*)&s_lds[odd ? 3 : 2][rc][0];

    float4 q0, q1, q2, q3;

#define F1_REGLOAD(cc)                                                         \
    {                                                                          \
        int nr_ = ((cc) < 8) ? K1_ROWS : 16;                                   \
        int items_ = nr_ * 16;                                                 \
        int it = t < items_ ? t : items_ - 1;                                  \
        int rr = it >> 4, cq = it & 15;                                        \
        const float4* xr =                                                     \
            (const float4*)(xp + ((cc) * K1_ROWS + rr) * 256) + cq;            \
        q0 = xr[0];                                                            \
        q1 = xr[16];                                                           \
        q2 = xr[32];                                                           \
        q3 = xr[48];                                                           \
    }

    F1_REGLOAD(0)

    for (int c = 0; c < NCHUNK; ++c) {
        int nr = (c < 8) ? K1_ROWS : 16;
        int items = nr * 16;

        // radix-4 combine (along w) + LDS write, from registers
        if (t < items) {
            int rr = t >> 4, cq = t & 15;
            float4 s02p, s02m, s13p, s13m;
            s02p.x = q0.x + q2.x; s02p.y = q0.y + q2.y;
            s02p.z = q0.z + q2.z; s02p.w = q0.w + q2.w;
            s02m.x = q0.x - q2.x; s02m.y = q0.y - q2.y;
            s02m.z = q0.z - q2.z; s02m.w = q0.w - q2.w;
            s13p.x = q1.x + q3.x; s13p.y = q1.y + q3.y;
            s13p.z = q1.z + q3.z; s13p.w = q1.w + q3.w;
            s13m.x = q1.x - q3.x; s13m.y = q1.y - q3.y;
            s13m.z = q1.z - q3.z; s13m.w = q1.w - q3.w;
            *(float4*)&s_lds[0][rr][cq * 4] = s02p;
            *(float4*)&s_lds[1][rr][cq * 4] = s02m;
            *(float4*)&s_lds[2][rr][cq * 4] = s13p;
            *(float4*)&s_lds[3][rr][cq * 4] = s13m;
        }
        __syncthreads();

        // prefetch next chunk into registers (in flight during compute)
        if (c + 1 < NCHUNK) F1_REGLOAD(c + 1)

        // 17-mode DFT of this chunk (radix-2 over l: 32 steps), 1 row/thread
        if (t < 510 && r < nr) {
            float pc = 1.f, ps = 0.f;
            float ar0 = 0, ai0 = 0;

#define K1_STEP(a0e, b0e, a0f, b0f)                                   \
  { float t0re = fmaf(k1c, (b0f), fmaf(cwv, (a0f), fmaf(ca, (b0e), (a0e)))); \
    float t0im = fmaf(k2c, (b0f), fmaf(swv, (a0f), cb * (b0e)));      \
    ar0 = fmaf(t0re, pc, ar0); ar0 = fmaf(-t0im, ps, ar0);            \
    ai0 = fmaf(t0re, ps, ai0); ai0 = fmaf(t0im, pc, ai0);             \
    float nps = fmaf(pc, sj, ps * cj);                                \
    pc = fmaf(pc, cj, -(ps * sj)); ps = nps; }

#pragma unroll 2
            for (int l4 = 0; l4 < 8; ++l4) {
                float4 va0 = A4[l4], vb0 = B4[l4];
                float4 vA0 = A4[8 + l4], vB0 = B4[8 + l4];  // l+32
                K1_STEP(va0.x, vb0.x, vA0.x, vB0.x)
                K1_STEP(va0.y, vb0.y, vA0.y, vB0.y)
                K1_STEP(va0.z, vb0.z, vA0.z, vB0.z)
                K1_STEP(va0.w, vb0.w, vA0.w, vB0.w)
            }
#undef K1_STEP

            int h = c * K1_ROWS + r;
            xs[h * 17 + j] = make_float2(ar0, ai0);
        }
        __syncthreads();
    }

    // K2: in-place radix-4 butterfly along h (stage 1: h vs h+128)
    for (int q = t; q < 2176; q += 512) {
        float2 a = xs[q], b = xs[q + 2176];
        xs[q] = make_float2(a.x + b.x, a.y + b.y);
        xs[q + 2176] = make_float2(a.x - b.x, a.y - b.y);
    }
    __syncthreads();

    for (int q = t; q < 544; q += 512) {
        int kx = q / 17, ky = q % 17;
        int kodd = kx & 1;
        float cA = kodd ? 0.f : ((kx & 2) ? -1.f : 1.f);
        float cB = kodd ? (((kx & 3) == 1) ? -1.f : 1.f) : 0.f;
        float cBn = -cB;
        const float2* Aq = xs + (kodd ? 2176 : 0) + ky;
        float cs, ss;
        sincospif((float)kx * (1.0f / 128.0f), &ss, &cs);
        ss = -ss;  // step e^{-2pi i kx/256}
        float pc = 1.f, psn = 0.f;
        float ar = 0.f, ai = 0.f;
#pragma unroll 4
        for (int m = 0; m < 64; ++m) {
            float2 a = Aq[m * 17];
            float2 b = Aq[1088 + m * 17];
            float yre = fmaf(cBn, b.y, fmaf(cA, b.x, a.x));
            float yim = fmaf(cB, b.x, fmaf(cA, b.y, a.y));
            ar = fmaf(yre, pc, ar); ar = fmaf(-yim, psn, ar);
            ai = fmaf(yre, psn, ai); ai = fmaf(yim, pc, ai);
            float npc = pc * cs - psn * ss;
            psn = pc * ss + psn * cs;
            pc = npc;
        }
        X2[(long)bc * 544 + q] = make_float2(ar, ai);
    }
#undef F1_REGLOAD
}

// ---------------------------------------------------------------------------
// F2C = k3+K4+K5 fused, one (b,ho) plane per block, 512 threads.
//  Phase A: dual-accumulator, unroll-4 pairwise (24 loads in flight)
//  Phase B: h-pair radix-2 (verified R13)
//  Phase C: wide LDS read + readlane -> scalar z; ky-fold (verified R12/R13)
// ---------------------------------------------------------------------------
__global__ __launch_bounds__(512) void f2c_inv(const float2* __restrict__ X2,
                                               const float* __restrict__ wr_g,
                                               const float* __restrict__ wi_g,
                                               const float* __restrict__ bias,
                                               float* __restrict__ out) {
    __shared__ float2 psh[544];
    __shared__ float2 zsh[4352];  // [h*17+ky]
    int t = threadIdx.x;
    int plane = blockIdx.x;  // 0..511 = b*64 + ho
    int b = plane >> 6;
    int ho = plane & 63;
    int n = ho >> 4;
    int o = ho & 15;

    // Phase A: per-(kx,ky) 64-deep channel reduction, 2 accumulator pairs
    for (int q = t; q < 544; q += 512) {
        const float2* xp = X2 + (long)b * 64 * 544 + q;
        const float* wrp = wr_g + ((long)(n * 64) * 16 + o) * 544 + q;
        const float* wip = wi_g + ((long)(n * 64) * 16 + o) * 544 + q;
        float ar = 0.f, ai = 0.f, ar2 = 0.f, ai2 = 0.f;
#pragma unroll 4
        for (int i = 0; i < 64; i += 2) {
            float2 xv0 = xp[i * 544];
            float w0r = wrp[i * 8704];
            float w0i = wip[i * 8704];
            float2 xv1 = xp[(i + 1) * 544];
            float w1r = wrp[(i + 1) * 8704];
            float w1i = wip[(i + 1) * 8704];
            ar = fmaf(xv0.x, w0r, fmaf(-xv0.y, w0i, ar));
            ai = fmaf(xv0.x, w0i, fmaf(xv0.y, w0r, ai));
            ar2 = fmaf(xv1.x, w1r, fmaf(-xv1.y, w1i, ar2));
            ai2 = fmaf(xv1.x, w1i, fmaf(xv1.y, w1r, ai2));
        }
        psh[q] = make_float2(ar + ar2, ai + ai2);
    }
    __syncthreads();

    // Phase B: h-pair radix-2 over kx. h = t&127, pair (h, h+128). (verified)
    {
        int h = t & 127;
        int grp = t >> 7;                        // 0..3, wave-uniform
        int kyb = (grp == 0) ? 0 : (4 * grp + 1);  // 0,5,9,13
        int cnt = (grp == 0) ? 5 : 4;
        float chh, shh;
        sincospif((float)h * (1.0f / 128.0f), &shh, &chh);  // step e^{+2pi i h/256}
        float pc = 1.f, psn = 0.f;
        float aer[5], aei[5], aor[5], aoi[5];
#pragma unroll
        for (int u = 0; u < 5; ++u) { aer[u] = 0.f; aei[u] = 0.f; aor[u] = 0.f; aoi[u] = 0.f; }

        const float2* pq = psh + kyb;
#pragma unroll
        for (int kx = 0; kx < 32; ++kx) {
#pragma unroll
            for (int u = 0; u < 5; ++u) {
                if (u < cnt) {
                    float2 v = pq[kx * 17 + u];
                    if ((kx & 1) == 0) {
                        aer[u] = fmaf(v.x, pc, fmaf(-v.y, psn, aer[u]));
                        aei[u] = fmaf(v.x, psn, fmaf(v.y, pc, aei[u]));
                    } else {
                        aor[u] = fmaf(v.x, pc, fmaf(-v.y, psn, aor[u]));
                        aoi[u] = fmaf(v.x, psn, fmaf(v.y, pc, aoi[u]));
                    }
                }
            }
            float npc = pc * chh - psn * shh;
            psn = pc * shh + psn * chh;
            pc = npc;
        }
#pragma unroll
        for (int u = 0; u < 5; ++u) {
            if (u < cnt) {
                int ky = kyb + u;
                zsh[h * 17 + ky] = make_float2(aer[u] + aor[u], aei[u] + aoi[u]);
                zsh[(h + 128) * 17 + ky] = make_float2(aer[u] - aor[u], aei[u] - aoi[u]);
            }
        }
    }
    __syncthreads();

    // Phase C: wide read + readlane (z is wave-uniform), ky-fold, hoisted table
    int wv = t >> 6;      // 0..7
    int lane = t & 63;
    float bv = bias[plane & 63];
    float c0, s0;
    sincospif((float)lane * (1.0f / 128.0f), &s0, &c0);  // e^{2pi i lane/256}
    float c8, s8;
    sincospif((float)lane * (1.0f / 16.0f), &s8, &c8);   // e^{2pi i 8 lane/256}

    float pcv[8], psv[8];
    {
        float pc = c0, ps = s0;
#pragma unroll
        for (int k = 0; k < 8; ++k) {
            pcv[k] = pc; psv[k] = ps;
            float nps = fmaf(pc, s0, ps * c0);
            pc = fmaf(pc, c0, -(ps * s0));
            ps = nps;
        }
    }

    const float inv = 1.0f / 65536.0f;
    const float inv2 = 2.0f / 65536.0f;
    long ob_plane = (long)plane * 65536;
    int li = lane < 34 ? lane : 33;

    for (int it16 = 0; it16 < 16; ++it16) {
        int r0 = it16 * 16 + wv * 2;
        // one wide read covers rows r0 and r0+1: zsh[r0*17 + 0..33]
        float2 zl = zsh[r0 * 17 + li];
        float zlx = zl.x, zly = zl.y;

#define RLF(v, l) __int_as_float(__builtin_amdgcn_readlane(__float_as_int(v), (l)))
        float zz0r[8], zz0i[8], zz1r[8], zz1i[8];
#pragma unroll
        for (int k = 0; k < 8; ++k) {
            float a0r = RLF(zlx, k + 1),  a0i = RLF(zly, k + 1);
            float b0r = RLF(zlx, k + 9),  b0i = RLF(zly, k + 9);
            float a1r = RLF(zlx, 18 + k), a1i = RLF(zly, 18 + k);
            float b1r = RLF(zlx, 26 + k), b1i = RLF(zly, 26 + k);
            zz0r[k] = fmaf(b0r, c8, fmaf(-b0i, s8, a0r));
            zz0i[k] = fmaf(b0r, s8, fmaf(b0i, c8, a0i));
            zz1r[k] = fmaf(b1r, c8, fmaf(-b1i, s8, a1r));
            zz1i[k] = fmaf(b1r, s8, fmaf(b1i, c8, a1i));
        }
        float base0 = RLF(zlx, 0) * inv + bv;
        float base1 = RLF(zlx, 17) * inv + bv;
#undef RLF

        float a00 = 0, a01 = 0, a02 = 0, a03 = 0;
        float a10 = 0, a11 = 0, a12 = 0, a13 = 0;
#pragma unroll
        for (int k = 0; k < 8; ++k) {
            int ky = k + 1;
            float A0 = zz0r[k] * pcv[k] - zz0i[k] * psv[k];
            float B0 = zz0r[k] * psv[k] + zz0i[k] * pcv[k];
            float A1 = zz1r[k] * pcv[k] - zz1i[k] * psv[k];
            float B1 = zz1r[k] * psv[k] + zz1i[k] * pcv[k];
            a00 += A0; a10 += A1;
            a01 += ((ky & 3) == 0) ? A0 : ((ky & 3) == 1) ? -B0 : ((ky & 3) == 2) ? -A0 : B0;
            a11 += ((ky & 3) == 0) ? A1 : ((ky & 3) == 1) ? -B1 : ((ky & 3) == 2) ? -A1 : B1;
            a02 += (ky & 1) ? -A0 : A0;
            a12 += (ky & 1) ? -A1 : A1;
            a03 += ((ky & 3) == 0) ? A0 : ((ky & 3) == 1) ? B0 : ((ky & 3) == 2) ? -A0 : -B0;
            a13 += ((ky & 3) == 0) ? A1 : ((ky & 3) == 1) ? B1 : ((ky & 3) == 2) ? -A1 : -B1;
        }
        long ob0 = ob_plane + (long)r0 * 256;
        long ob1 = ob0 + 256;
        out[ob0 + lane]       = fmaf(a00, inv2, base0);
        out[ob0 + 64 + lane]  = fmaf(a01, inv2, base0);
        out[ob0 + 128 + lane] = fmaf(a02, inv2, base0);
        out[ob0 + 192 + lane] = fmaf(a03, inv2, base0);
        out[ob1 + lane]       = fmaf(a10, inv2, base1);
        out[ob1 + 64 + lane]  = fmaf(a11, inv2, base1);
        out[ob1 + 128 + lane] = fmaf(a12, inv2, base1);
        out[ob1 + 192 + lane] = fmaf(a13, inv2, base1);
    }
}

extern "C" void kernel_launch(void* const* d_in, const int* in_sizes, int n_in,
                              void* d_out, int out_size, void* d_ws, size_t ws_size,
                              hipStream_t stream) {
    const float* x = (const float*)d_in[0];
    const float* wr = (const float*)d_in[1];
    const float* wi = (const float*)d_in[2];
    const float* bias = (const float*)d_in[3];
    float* out = (float*)d_out;
    float* ws = (float*)d_ws;

    float2* X2 = (float2*)(ws + 4456960);

    hipLaunchKernelGGL(f1_fw, dim3(512), dim3(512), 0, stream, x, X2);
    hipLaunchKernelGGL(f2c_inv, dim3(512), dim3(512), 0, stream, X2, wr, wi, bias, out);
}